// Round 3
// baseline (408.099 us; speedup 1.0000x reference)
//
#include <hip/hip_runtime.h>

#define NT 128
#define SS 512

typedef float f32x2 __attribute__((ext_vector_type(2)));

__device__ __forceinline__ int rdlane_i(float v, int lane) {
    return __builtin_amdgcn_readlane(__float_as_int(v), lane);
}
__device__ __forceinline__ int fexp_of(float x) {
    return (int)((__float_as_uint(x) >> 23) & 0xFFu) - 127;
}
// barrier draining only LDS ops — global prefetches stay in flight
__device__ __forceinline__ void lds_barrier() {
    asm volatile("s_waitcnt lgkmcnt(0)\n\ts_barrier" ::: "memory");
}
// acc += {q,q} * etr, with the broadcast pair living in an SGPR pair
// (VOP3P allows one scalar source; SALU builds the pair off the VALU pipe)
__device__ __forceinline__ void pkfma_s(f32x2& acc, unsigned long long qq, f32x2 etr) {
    asm("v_pk_fma_f32 %0, %1, %2, %0" : "+v"(acc) : "s"(qq), "v"(etr));
}
__device__ __forceinline__ unsigned long long dup2(int q) {
    unsigned u = (unsigned)q;
    return ((unsigned long long)u << 32) | u;
}

__global__ void zero_out_kernel(float* out) { out[0] = 0.0f; }

// W=2 waves: minimal cross-wave exchange (1 write + 1 read + 2-wave barrier).
// Wave w owns rows/states 64w..64w+63; lane l holds state 64w+l.
// Table packed {own col, other col} so exchange is symmetric: write s2.y, keep s2.x.
__global__ __launch_bounds__(128, 1) void crf_fwd_kernel(
    const float* __restrict__ emissions,        // [B, S, NT] f32
    const int* __restrict__ tags,               // [B, S]
    const unsigned char* __restrict__ mask,     // [B, S]
    const float* __restrict__ trans,            // [NT, NT] f32
    float* __restrict__ out)                    // [1] f32
{
    const int b   = blockIdx.x;                 // one batch per block
    const int tid = threadIdx.x;                // 0..127
    const int l   = tid & 63;
    const int w   = tid >> 6;                   // wave 0 or 1
    const int st  = (w << 6) + l;               // owned state (no dup)
    const int co  = ((w ^ 1) << 6) + l;         // cross column this lane accumulates

    __shared__ float pb[2][2][64];              // [writer-wave][parity][lane]
    __shared__ int   kslot;
    __shared__ float redf[2];
    __shared__ float redg[2];

    const float*         emB = emissions + (size_t)b * SS * NT;
    const int*           tgB = tags + b * SS;
    const unsigned char* mkB = mask + b * SS;

    // ---- gold score fully hoisted off the recursion ----
    float gold = 0.0f;
    #pragma unroll
    for (int k = 0; k < SS / 128; k++) {
        int t    = tid + 128 * k;
        int tg   = tgB[t];
        float mk = mkB[t] ? 1.0f : 0.0f;
        float a  = emB[(size_t)t * NT + tg];
        if (t > 0) a += trans[tgB[t - 1] * NT + tg];
        gold += a * mk;
    }

    // ---- expT: own 64 rows, packed {own col, cross col} -> 128 VGPRs ----
    f32x2 eTr[64];
    #pragma unroll
    for (int r = 0; r < 64; r++) {
        const float* row = trans + (size_t)((w << 6) + r) * NT;
        f32x2 v; v.x = __expf(row[st]); v.y = __expf(row[co]);
        eTr[r] = v;
    }

    // ---- init: p = exp(a0 - M0) ----
    float a0 = emB[st];
    {
        float v = a0;
        #pragma unroll
        for (int o = 32; o > 0; o >>= 1) v = fmaxf(v, __shfl_xor(v, o));
        if (l == 0) redf[w] = v;
    }
    __syncthreads();
    const float M0 = fmaxf(redf[0], redf[1]);

    float p = __expf(a0 - M0);                  // alpha-hat for state st
    float S = 0.0f;
    int K = 0, kv_own = 0;

    // ---- emission pipeline: loads 4 deep, exp 2 steps off-chain ----
    float ex_o = __expf(emB[(size_t)1 * NT + st]);
    float ex_e = __expf(emB[(size_t)2 * NT + st]);
    float pd_o = emB[(size_t)3 * NT + st];
    float pd_e = emB[(size_t)4 * NT + st];

    // matvec over own 64 rows: readlane (VALU) + SALU pair-build + pk_fma
    auto matvec = [&]() -> f32x2 {
        f32x2 A0 = {0.f,0.f}, A1 = {0.f,0.f}, A2 = {0.f,0.f}, A3 = {0.f,0.f};
        #pragma unroll
        for (int r = 0; r < 64; r += 4) {
            unsigned long long q0 = dup2(rdlane_i(p, r + 0));
            unsigned long long q1 = dup2(rdlane_i(p, r + 1));
            unsigned long long q2 = dup2(rdlane_i(p, r + 2));
            unsigned long long q3 = dup2(rdlane_i(p, r + 3));
            pkfma_s(A0, q0, eTr[r + 0]);
            pkfma_s(A1, q1, eTr[r + 1]);
            pkfma_s(A2, q2, eTr[r + 2]);
            pkfma_s(A3, q3, eTr[r + 3]);
        }
        return (A0 + A1) + (A2 + A3);           // {own-col partial, cross-col partial}
    };
    auto rot = [&](int t, float& pd, float& ex) {
        float nr = pd;
        int tn = t + 4; if (tn > SS - 1) tn = SS - 1;
        pd = emB[(size_t)tn * NT + st];
        ex = __expf(nr);
    };

    // ---- forward recursion: groups of 4 steps; rescale at sub-step 0 ----
    #pragma unroll 1
    for (int t = 1; t < SS; t += 4) {
        {   // sub 0 (parity 1): apply K, propose next kv (state-0 anchor, no shuffle)
            f32x2 s2 = matvec();
            pb[w][1][l] = s2.y;
            lds_barrier();
            float sn = (s2.x + pb[w ^ 1][1][l]) * ex_o;
            p = ldexpf(sn, -K);
            S += (float)K;
            kv_own = fexp_of(p);                // only wave0-lane0's value is used
            rot(t, pd_o, ex_o);
        }
        if (t + 1 < SS) {   // sub 1 (parity 0): K anchor rides the barrier
            f32x2 s2 = matvec();
            pb[w][0][l] = s2.y;
            if (w == 0 && l == 0) kslot = kv_own;
            lds_barrier();
            p = (s2.x + pb[w ^ 1][0][l]) * ex_e;
            K = kslot;                          // uniform broadcast read, off-chain
            rot(t + 1, pd_e, ex_e);
        }
        if (t + 2 < SS) {   // sub 2 (parity 1)
            f32x2 s2 = matvec();
            pb[w][1][l] = s2.y;
            lds_barrier();
            p = (s2.x + pb[w ^ 1][1][l]) * ex_o;
            rot(t + 2, pd_o, ex_o);
        }
        if (t + 3 < SS) {   // sub 3 (parity 0)
            f32x2 s2 = matvec();
            pb[w][0][l] = s2.y;
            lds_barrier();
            p = (s2.x + pb[w ^ 1][0][l]) * ex_e;
            rot(t + 3, pd_e, ex_e);
        }
    }

    // ---- epilogue: partition = M0 + S*ln2 + log Σ p̂ ; reduce gold ----
    {
        float sw = p;                           // one state per lane, no dup
        float g  = gold;
        #pragma unroll
        for (int o = 32; o > 0; o >>= 1) {
            sw += __shfl_xor(sw, o);
            g  += __shfl_xor(g, o);
        }
        if (l == 0) { redf[w] = sw; redg[w] = g; }
    }
    __syncthreads();
    if (tid == 0) {
        float tot  = redf[0] + redf[1];
        float part = M0 + S * 0.69314718055994531f + __logf(tot);
        float gt   = redg[0] + redg[1];
        atomicAdd(out, part - gt);
    }
}

extern "C" void kernel_launch(void* const* d_in, const int* in_sizes, int n_in,
                              void* d_out, int out_size, void* d_ws, size_t ws_size,
                              hipStream_t stream) {
    const float*         emissions = (const float*)d_in[0];
    const int*           tags      = (const int*)d_in[1];
    const unsigned char* mask      = (const unsigned char*)d_in[2];
    const float*         trans     = (const float*)d_in[3];
    float*               out       = (float*)d_out;

    zero_out_kernel<<<1, 1, 0, stream>>>(out);
    crf_fwd_kernel<<<256, 128, 0, stream>>>(emissions, tags, mask, trans, out);
}

// Round 4
// 339.928 us; speedup vs baseline: 1.2005x; 1.2005x over previous
//
#include <hip/hip_runtime.h>

#define NT 128
#define SS 512

typedef float f32x2 __attribute__((ext_vector_type(2)));
typedef float f32x4 __attribute__((ext_vector_type(4)));

__device__ __forceinline__ int fexp_of(float x) {
    return (int)((__float_as_uint(x) >> 23) & 0xFFu) - 127;
}
// barrier draining only LDS ops — global prefetches stay in flight
__device__ __forceinline__ void lds_barrier() {
    asm volatile("s_waitcnt lgkmcnt(0)\n\ts_barrier" ::: "memory");
}
__device__ __forceinline__ f32x2 lo2(f32x4 v) { return __builtin_shufflevector(v, v, 0, 1); }
__device__ __forceinline__ f32x2 hi2(f32x4 v) { return __builtin_shufflevector(v, v, 2, 3); }

__global__ void zero_out_kernel(float* out) { out[0] = 0.0f; }

// Column-split: lane tid owns state tid (W=2, 128 lanes = 128 states) and holds
// the full exp(T) column (128 rows packed as 64 f32x2 = 128 VGPRs). Alpha is
// broadcast from LDS via uniform-address ds_read_b128 (no readlane, no combine
// tree). Exchange per step = 1 ds_write_b32 + one 2-wave barrier.
// Rescale every step via the uniform anchor alpha[0] — zero communication.
__global__ __launch_bounds__(128, 1) void crf_fwd_kernel(
    const float* __restrict__ emissions,        // [B, S, NT] f32
    const int* __restrict__ tags,               // [B, S]
    const unsigned char* __restrict__ mask,     // [B, S]
    const float* __restrict__ trans,            // [NT, NT] f32
    float* __restrict__ out)                    // [1] f32
{
    const int b   = blockIdx.x;                 // one batch per block
    const int tid = threadIdx.x;                // 0..127
    const int l   = tid & 63;
    const int w   = tid >> 6;                   // wave 0 or 1
    const int st  = tid;                        // owned output state/column

    __shared__ __align__(16) float abufF[2][NT];    // [parity][state]
    __shared__ float redf[2];
    __shared__ float redg[2];

    const float*         emB = emissions + (size_t)b * SS * NT;
    const int*           tgB = tags + b * SS;
    const unsigned char* mkB = mask + b * SS;

    // ---- gold score fully hoisted off the recursion ----
    float gold = 0.0f;
    #pragma unroll
    for (int kk = 0; kk < SS / 128; kk++) {
        int t    = tid + 128 * kk;
        int tg   = tgB[t];
        float mk = mkB[t] ? 1.0f : 0.0f;
        float a  = emB[(size_t)t * NT + tg];
        if (t > 0) a += trans[tgB[t - 1] * NT + tg];
        gold += a * mk;
    }

    // ---- expT column st: rows packed in pairs -> 64 f32x2 = 128 VGPRs ----
    f32x2 eTr[NT / 2];
    #pragma unroll
    for (int r = 0; r < NT / 2; r++) {
        f32x2 v;
        v.x = __expf(trans[(size_t)(2 * r)     * NT + st]);
        v.y = __expf(trans[(size_t)(2 * r + 1) * NT + st]);
        eTr[r] = v;
    }

    // ---- init: p = exp(a0 - M0), publish alpha_0 ----
    float a0 = emB[st];
    {
        float v = a0;
        #pragma unroll
        for (int o = 32; o > 0; o >>= 1) v = fmaxf(v, __shfl_xor(v, o));
        if (l == 0) redf[w] = v;
    }
    __syncthreads();
    const float M0 = fmaxf(redf[0], redf[1]);

    float p = __expf(a0 - M0);
    abufF[0][st] = p;

    // ---- emission pipeline: loads 4 deep, exp 2 steps off-chain ----
    float ex_o = __expf(emB[(size_t)1 * NT + st]);
    float ex_e = __expf(emB[(size_t)2 * NT + st]);
    float pd_o = emB[(size_t)3 * NT + st];
    float pd_e = emB[(size_t)4 * NT + st];

    int S_int = 0;
    lds_barrier();                              // alpha_0 visible to both waves

    // full matvec for own column from LDS broadcast; per-step anchor rescale
    auto step = [&](int pr, float exv) -> float {
        const f32x4* ap = (const f32x4*)abufF[pr];
        f32x2 A0 = {0.f,0.f}, A1 = {0.f,0.f}, A2 = {0.f,0.f}, A3 = {0.f,0.f};
        float q0 = 0.0f;
        #pragma unroll
        for (int j = 0; j < 8; j++) {
            f32x4 v0 = ap[4 * j + 0];           // alphas 16j .. 16j+3
            f32x4 v1 = ap[4 * j + 1];
            f32x4 v2 = ap[4 * j + 2];
            f32x4 v3 = ap[4 * j + 3];
            if (j == 0) q0 = v0.x;              // uniform anchor alpha[0]
            A0 = __builtin_elementwise_fma(lo2(v0), eTr[8 * j + 0], A0);
            A1 = __builtin_elementwise_fma(hi2(v0), eTr[8 * j + 1], A1);
            A2 = __builtin_elementwise_fma(lo2(v1), eTr[8 * j + 2], A2);
            A3 = __builtin_elementwise_fma(hi2(v1), eTr[8 * j + 3], A3);
            A0 = __builtin_elementwise_fma(lo2(v2), eTr[8 * j + 4], A0);
            A1 = __builtin_elementwise_fma(hi2(v2), eTr[8 * j + 5], A1);
            A2 = __builtin_elementwise_fma(lo2(v3), eTr[8 * j + 6], A2);
            A3 = __builtin_elementwise_fma(hi2(v3), eTr[8 * j + 7], A3);
        }
        int k = fexp_of(q0);                    // identical in every lane
        S_int += k;
        float scale = __int_as_float((unsigned)(127 - k) << 23);   // 2^-k exact
        f32x2 s2 = (A0 + A1) + (A2 + A3);
        return (s2.x + s2.y) * (exv * scale);
    };
    auto rot = [&](int t, float& pd, float& ex) {
        float nr = pd;
        int tn = t + 4; if (tn > SS - 1) tn = SS - 1;
        pd = emB[(size_t)tn * NT + st];
        ex = __expf(nr);
    };

    // ---- forward recursion: 2 steps/iter keeps parity compile-time ----
    #pragma unroll 1
    for (int t = 1; t < SS; t += 2) {
        {   // odd t: read buf0, write buf1
            float sn = step(0, ex_o);
            p = sn;
            abufF[1][st] = sn;
            rot(t, pd_o, ex_o);                 // fills barrier shadow
            lds_barrier();
        }
        if (t + 1 < SS) {                       // even t: read buf1, write buf0
            float sn = step(1, ex_e);
            p = sn;
            abufF[0][st] = sn;
            rot(t + 1, pd_e, ex_e);
            lds_barrier();
        }
    }

    // ---- epilogue: partition = M0 + S*ln2 + log Σ p̂ ; reduce gold ----
    {
        float sw = p;                           // one state per lane, no dup
        float g  = gold;
        #pragma unroll
        for (int o = 32; o > 0; o >>= 1) {
            sw += __shfl_xor(sw, o);
            g  += __shfl_xor(g, o);
        }
        if (l == 0) { redf[w] = sw; redg[w] = g; }
    }
    __syncthreads();
    if (tid == 0) {
        float tot  = redf[0] + redf[1];
        float part = M0 + (float)S_int * 0.69314718055994531f + __logf(tot);
        float gt   = redg[0] + redg[1];
        atomicAdd(out, part - gt);
    }
}

extern "C" void kernel_launch(void* const* d_in, const int* in_sizes, int n_in,
                              void* d_out, int out_size, void* d_ws, size_t ws_size,
                              hipStream_t stream) {
    const float*         emissions = (const float*)d_in[0];
    const int*           tags      = (const int*)d_in[1];
    const unsigned char* mask      = (const unsigned char*)d_in[2];
    const float*         trans     = (const float*)d_in[3];
    float*               out       = (float*)d_out;

    zero_out_kernel<<<1, 1, 0, stream>>>(out);
    crf_fwd_kernel<<<256, 128, 0, stream>>>(emissions, tags, mask, trans, out);
}

// Round 5
// 293.466 us; speedup vs baseline: 1.3906x; 1.1583x over previous
//
#include <hip/hip_runtime.h>

#define NT 128
#define SS 512

typedef float f32x2 __attribute__((ext_vector_type(2)));

__device__ __forceinline__ float rdlanef(float v, int lane) {
    return __int_as_float(__builtin_amdgcn_readlane(__float_as_int(v), lane));
}
__device__ __forceinline__ int fexp_of(float x) {
    return (int)((__float_as_uint(x) >> 23) & 0xFFu) - 127;
}
// barrier draining only LDS ops — global prefetches stay in flight
__device__ __forceinline__ void lds_barrier() {
    asm volatile("s_waitcnt lgkmcnt(0)\n\ts_barrier" ::: "memory");
}

__global__ void zero_out_kernel(float* out) { out[0] = 0.0f; }

// W=2 row-split (R3 structure: 1 b32 write + 2-wave barrier + 1 b32 read per
// step), but alpha broadcast via batched v_readlane -> SGPR -> scalar-src0
// v_fmac_f32 (plain C++ fmaf with wave-uniform multiplier; SGPR folds into
// VALU src0). No dup2 SALU chain, no inline-asm FMA, no LDS broadcast reads.
__global__ __launch_bounds__(128, 1) void crf_fwd_kernel(
    const float* __restrict__ emissions,        // [B, S, NT] f32
    const int* __restrict__ tags,               // [B, S]
    const unsigned char* __restrict__ mask,     // [B, S]
    const float* __restrict__ trans,            // [NT, NT] f32
    float* __restrict__ out)                    // [1] f32
{
    const int b   = blockIdx.x;                 // one batch per block
    const int tid = threadIdx.x;                // 0..127
    const int l   = tid & 63;
    const int w   = tid >> 6;                   // wave 0 or 1
    const int st  = (w << 6) + l;               // owned state (lane-resident alpha)
    const int co  = ((w ^ 1) << 6) + l;         // mirrored column this lane also sums

    __shared__ float pb[2][2][64];              // [writer-wave][parity][lane]
    __shared__ int   kslot;
    __shared__ float redf[2];
    __shared__ float redg[2];

    const float*         emB = emissions + (size_t)b * SS * NT;
    const int*           tgB = tags + b * SS;
    const unsigned char* mkB = mask + b * SS;

    // ---- gold score fully hoisted off the recursion ----
    float gold = 0.0f;
    #pragma unroll
    for (int k = 0; k < SS / 128; k++) {
        int t    = tid + 128 * k;
        int tg   = tgB[t];
        float mk = mkB[t] ? 1.0f : 0.0f;
        float a  = emB[(size_t)t * NT + tg];
        if (t > 0) a += trans[tgB[t - 1] * NT + tg];
        gold += a * mk;
    }

    // ---- expT: own 64 rows, cols {own st, mirror co} -> 128 VGPRs ----
    float eTx[64], eTy[64];
    #pragma unroll
    for (int r = 0; r < 64; r++) {
        const float* row = trans + (size_t)((w << 6) + r) * NT;
        eTx[r] = __expf(row[st]);
        eTy[r] = __expf(row[co]);
    }

    // ---- init: p = exp(a0 - M0) ----
    float a0 = emB[st];
    {
        float v = a0;
        #pragma unroll
        for (int o = 32; o > 0; o >>= 1) v = fmaxf(v, __shfl_xor(v, o));
        if (l == 0) redf[w] = v;
    }
    __syncthreads();
    const float M0 = fmaxf(redf[0], redf[1]);

    float p = __expf(a0 - M0);                  // alpha-hat for state st
    float S = 0.0f;
    int K = 0, kv_own = 0;

    // ---- emission pipeline: loads 4 deep, exp 2 steps off-chain ----
    float ex_o = __expf(emB[(size_t)1 * NT + st]);
    float ex_e = __expf(emB[(size_t)2 * NT + st]);
    float pd_o = emB[(size_t)3 * NT + st];
    float pd_e = emB[(size_t)4 * NT + st];

    // matvec over own 64 rows: readlane (SGPR) + scalar-src fmac, 8 accumulators
    auto matvec = [&]() -> f32x2 {
        float A0x = 0.f, A1x = 0.f, A2x = 0.f, A3x = 0.f;
        float A0y = 0.f, A1y = 0.f, A2y = 0.f, A3y = 0.f;
        #pragma unroll
        for (int r = 0; r < 64; r += 4) {
            float q0 = rdlanef(p, r + 0);
            float q1 = rdlanef(p, r + 1);
            float q2 = rdlanef(p, r + 2);
            float q3 = rdlanef(p, r + 3);
            A0x = fmaf(q0, eTx[r + 0], A0x);  A0y = fmaf(q0, eTy[r + 0], A0y);
            A1x = fmaf(q1, eTx[r + 1], A1x);  A1y = fmaf(q1, eTy[r + 1], A1y);
            A2x = fmaf(q2, eTx[r + 2], A2x);  A2y = fmaf(q2, eTy[r + 2], A2y);
            A3x = fmaf(q3, eTx[r + 3], A3x);  A3y = fmaf(q3, eTy[r + 3], A3y);
        }
        f32x2 s2;
        s2.x = (A0x + A1x) + (A2x + A3x);       // own-col partial (rows 64w..64w+63)
        s2.y = (A0y + A1y) + (A2y + A3y);       // mirror-col partial
        return s2;
    };
    auto rot = [&](int t, float& pd, float& ex) {
        float nr = pd;
        int tn = t + 4; if (tn > SS - 1) tn = SS - 1;
        pd = emB[(size_t)tn * NT + st];
        ex = __expf(nr);
    };

    // ---- forward recursion: groups of 4 steps; rescale at sub-step 0 ----
    #pragma unroll 1
    for (int t = 1; t < SS; t += 4) {
        {   // sub 0 (parity 1): apply K, propose next kv (state-0 anchor)
            f32x2 s2 = matvec();
            pb[w][1][l] = s2.y;
            lds_barrier();
            float sn = (s2.x + pb[w ^ 1][1][l]) * ex_o;
            p = ldexpf(sn, -K);
            S += (float)K;
            kv_own = fexp_of(p);                // only wave0-lane0's value is used
            rot(t, pd_o, ex_o);
        }
        if (t + 1 < SS) {   // sub 1 (parity 0): K anchor rides the barrier
            f32x2 s2 = matvec();
            pb[w][0][l] = s2.y;
            if (w == 0 && l == 0) kslot = kv_own;
            lds_barrier();
            p = (s2.x + pb[w ^ 1][0][l]) * ex_e;
            K = kslot;                          // uniform broadcast read, off-chain
            rot(t + 1, pd_e, ex_e);
        }
        if (t + 2 < SS) {   // sub 2 (parity 1)
            f32x2 s2 = matvec();
            pb[w][1][l] = s2.y;
            lds_barrier();
            p = (s2.x + pb[w ^ 1][1][l]) * ex_o;
            rot(t + 2, pd_o, ex_o);
        }
        if (t + 3 < SS) {   // sub 3 (parity 0)
            f32x2 s2 = matvec();
            pb[w][0][l] = s2.y;
            lds_barrier();
            p = (s2.x + pb[w ^ 1][0][l]) * ex_e;
            rot(t + 3, pd_e, ex_e);
        }
    }

    // ---- epilogue: partition = M0 + S*ln2 + log Σ p̂ ; reduce gold ----
    {
        float sw = p;                           // one state per lane, no dup
        float g  = gold;
        #pragma unroll
        for (int o = 32; o > 0; o >>= 1) {
            sw += __shfl_xor(sw, o);
            g  += __shfl_xor(g, o);
        }
        if (l == 0) { redf[w] = sw; redg[w] = g; }
    }
    __syncthreads();
    if (tid == 0) {
        float tot  = redf[0] + redf[1];
        float part = M0 + S * 0.69314718055994531f + __logf(tot);
        float gt   = redg[0] + redg[1];
        atomicAdd(out, part - gt);
    }
}

extern "C" void kernel_launch(void* const* d_in, const int* in_sizes, int n_in,
                              void* d_out, int out_size, void* d_ws, size_t ws_size,
                              hipStream_t stream) {
    const float*         emissions = (const float*)d_in[0];
    const int*           tags      = (const int*)d_in[1];
    const unsigned char* mask      = (const unsigned char*)d_in[2];
    const float*         trans     = (const float*)d_in[3];
    float*               out       = (float*)d_out;

    zero_out_kernel<<<1, 1, 0, stream>>>(out);
    crf_fwd_kernel<<<256, 128, 0, stream>>>(emissions, tags, mask, trans, out);
}